// Round 1
// baseline (2688.010 us; speedup 1.0000x reference)
//
#include <hip/hip_runtime.h>
#include <math.h>

#define TLEN 256
#define BATCH 4
#define DMODEL 768
#define DINNER 1536
#define NSTATE 16
#define DTRANK 48
#define NLAYER 4
#define XDBL_LD 80

// ---------------- embed: x[bt,d] = emb[ids[bt],d] + pos[t,d] ----------------
__global__ __launch_bounds__(256) void embed_k(const int* __restrict__ ids,
                                               const float* __restrict__ emb,
                                               const float* __restrict__ pos,
                                               float* __restrict__ x) {
    int idx = blockIdx.x * 256 + threadIdx.x;       // < B*T*DMODEL
    int d = idx % DMODEL;
    int bt = idx / DMODEL;
    int t = bt % TLEN;
    x[idx] = emb[(size_t)ids[bt] * DMODEL + d] + pos[t * DMODEL + d];
}

// ---------------- tiled fp32 GEMM: C[m,n] (+)= act(sum_k A[m,k]*B[n,k] + bias[n])
// A row-major (lda), B row-major (ldb) with rows = output features (i.e. B^T matmul)
// ACT: 0=none, 1=softplus.  ADDC: 0=overwrite, 1=accumulate into C.
#define BM 64
#define BN 64
#define BKK 16
template <int ACT, int ADDC>
__global__ __launch_bounds__(256) void gemm_k(const float* __restrict__ A, int lda,
                                              const float* __restrict__ Bw, int ldb,
                                              float* __restrict__ C, int ldc,
                                              int M, int N, int K,
                                              const float* __restrict__ bias) {
    __shared__ float As[BKK][BM + 1];
    __shared__ float Bs[BKK][BN + 1];
    int tid = threadIdx.x;
    int bm = blockIdx.x * BM;
    int bn = blockIdx.y * BN;
    int loadRow = tid >> 2;          // 0..63
    int loadK = (tid & 3) * 4;       // 0,4,8,12
    int tm = (tid >> 4) * 4;
    int tn = (tid & 15) * 4;
    float acc[4][4] = {};
    for (int k0 = 0; k0 < K; k0 += BKK) {
        // A tile (M rows always in-bounds for our shapes; K multiple of 16)
        {
            const float4 v = *reinterpret_cast<const float4*>(
                A + (size_t)(bm + loadRow) * lda + k0 + loadK);
            As[loadK + 0][loadRow] = v.x;
            As[loadK + 1][loadRow] = v.y;
            As[loadK + 2][loadRow] = v.z;
            As[loadK + 3][loadRow] = v.w;
        }
        // B tile (guard rows: N=80 case)
        {
            float4 v = {0.f, 0.f, 0.f, 0.f};
            int gn = bn + loadRow;
            if (gn < N)
                v = *reinterpret_cast<const float4*>(
                    Bw + (size_t)gn * ldb + k0 + loadK);
            Bs[loadK + 0][loadRow] = v.x;
            Bs[loadK + 1][loadRow] = v.y;
            Bs[loadK + 2][loadRow] = v.z;
            Bs[loadK + 3][loadRow] = v.w;
        }
        __syncthreads();
#pragma unroll
        for (int k = 0; k < BKK; ++k) {
            float a0 = As[k][tm + 0], a1 = As[k][tm + 1], a2 = As[k][tm + 2], a3 = As[k][tm + 3];
            float b0 = Bs[k][tn + 0], b1 = Bs[k][tn + 1], b2 = Bs[k][tn + 2], b3 = Bs[k][tn + 3];
            acc[0][0] += a0 * b0; acc[0][1] += a0 * b1; acc[0][2] += a0 * b2; acc[0][3] += a0 * b3;
            acc[1][0] += a1 * b0; acc[1][1] += a1 * b1; acc[1][2] += a1 * b2; acc[1][3] += a1 * b3;
            acc[2][0] += a2 * b0; acc[2][1] += a2 * b1; acc[2][2] += a2 * b2; acc[2][3] += a2 * b3;
            acc[3][0] += a3 * b0; acc[3][1] += a3 * b1; acc[3][2] += a3 * b2; acc[3][3] += a3 * b3;
        }
        __syncthreads();
    }
#pragma unroll
    for (int i = 0; i < 4; ++i) {
#pragma unroll
        for (int j = 0; j < 4; ++j) {
            int gm = bm + tm + i;
            int gn = bn + tn + j;
            if (gn < N) {
                float v = acc[i][j];
                if (bias) v += bias[gn];
                if (ACT == 1) {  // stable softplus
                    v = (v > 0.f) ? v + log1pf(expf(-v)) : log1pf(expf(v));
                }
                size_t idx = (size_t)gm * ldc + gn;
                C[idx] = (ADDC ? C[idx] : 0.f) + v;
            }
        }
    }
}

// ---------------- causal depthwise conv (K=4) + bias + SiLU ----------------
// reads xi_pre = xz[:, 0:DINNER], writes xi (B*T, DINNER)
__global__ __launch_bounds__(256) void conv_k(const float* __restrict__ xz,
                                              const float* __restrict__ cw,
                                              const float* __restrict__ cb,
                                              float* __restrict__ xi) {
    int idx = blockIdx.x * 256 + threadIdx.x;  // < B*T*DINNER
    int d = idx % DINNER;
    int bt = idx / DINNER;
    int t = bt % TLEN;
    int b = bt / TLEN;
    float s = cb[d];
#pragma unroll
    for (int k = 0; k < 4; ++k) {
        int tt = t + k - 3;
        if (tt >= 0) s += cw[d * 4 + k] * xz[(size_t)(b * TLEN + tt) * (2 * DINNER) + d];
    }
    xi[idx] = s / (1.f + expf(-s));  // SiLU
}

// ---------------- fused selective scan + D*xi + *silu(z) ----------------
// one thread per (b,d); 16 states in registers
__global__ __launch_bounds__(256) void scan_k(const float* __restrict__ dtb,
                                              const float* __restrict__ xi,
                                              const float* __restrict__ xdbl,
                                              const float* __restrict__ xz,
                                              const float* __restrict__ Alog,
                                              const float* __restrict__ Dsk,
                                              float* __restrict__ yb) {
    int d = blockIdx.x * 256 + threadIdx.x;  // 0..1535  (grid.x = 6)
    int b = blockIdx.y;                      // 0..3
    float a[NSTATE], h[NSTATE];
#pragma unroll
    for (int n = 0; n < NSTATE; ++n) {
        a[n] = -expf(Alog[(size_t)d * NSTATE + n]);
        h[n] = 0.f;
    }
    float Dv = Dsk[d];
    for (int t = 0; t < TLEN; ++t) {
        int row = b * TLEN + t;
        float dtv = dtb[(size_t)row * DINNER + d];
        float xiv = xi[(size_t)row * DINNER + d];
        const float* bc = xdbl + (size_t)row * XDBL_LD;
        float dx = dtv * xiv;
        float y = 0.f;
#pragma unroll
        for (int n = 0; n < NSTATE; ++n) {
            float dA = expf(dtv * a[n]);
            h[n] = dA * h[n] + dx * bc[DTRANK + n];
            y += h[n] * bc[DTRANK + NSTATE + n];
        }
        y += Dv * xiv;
        float z = xz[(size_t)row * (2 * DINNER) + DINNER + d];
        y *= z / (1.f + expf(-z));
        yb[(size_t)row * DINNER + d] = y;
    }
}

// ---------------- RMSNorm ----------------
__global__ __launch_bounds__(256) void rmsnorm_k(const float* __restrict__ x,
                                                 const float* __restrict__ nw,
                                                 float* __restrict__ out) {
    int row = blockIdx.x;  // B*T rows
    const float* xr = x + (size_t)row * DMODEL;
    int tid = threadIdx.x;
    float s = 0.f;
    for (int d = tid; d < DMODEL; d += 256) {
        float v = xr[d];
        s += v * v;
    }
#pragma unroll
    for (int off = 32; off >= 1; off >>= 1) s += __shfl_down(s, off);
    __shared__ float red[4];
    __shared__ float scale;
    int wid = tid >> 6, lane = tid & 63;
    if (lane == 0) red[wid] = s;
    __syncthreads();
    if (tid == 0) {
        float tot = red[0] + red[1] + red[2] + red[3];
        scale = rsqrtf(tot / (float)DMODEL + 1e-5f);
    }
    __syncthreads();
    float sc = scale;
    for (int d = tid; d < DMODEL; d += 256)
        out[(size_t)row * DMODEL + d] = xr[d] * sc * nw[d];
}

extern "C" void kernel_launch(void* const* d_in, const int* in_sizes, int n_in,
                              void* d_out, int out_size, void* d_ws, size_t ws_size,
                              hipStream_t stream) {
    const int* ids = (const int*)d_in[0];
    const float* emb = (const float*)d_in[1];
    const float* pos = (const float*)d_in[2];
    const float* ipw = (const float*)d_in[3];
    const float* cw = (const float*)d_in[4];
    const float* cb = (const float*)d_in[5];
    const float* xpw = (const float*)d_in[6];
    const float* dpw = (const float*)d_in[7];
    const float* dpb = (const float*)d_in[8];
    const float* Alog = (const float*)d_in[9];
    const float* Dsk = (const float*)d_in[10];
    const float* opw = (const float*)d_in[11];
    const float* nw = (const float*)d_in[12];

    const int NTOK = BATCH * TLEN;  // 1024
    float* x = (float*)d_ws;                     // 1024*768
    float* xz = x + NTOK * DMODEL;               // 1024*3072
    float* xi = xz + NTOK * 2 * DINNER;          // 1024*1536
    float* xdbl = xi + NTOK * DINNER;            // 1024*80
    float* dtb = xdbl + NTOK * XDBL_LD;          // 1024*1536
    float* yb = dtb + NTOK * DINNER;             // 1024*1536

    embed_k<<<NTOK * DMODEL / 256, 256, 0, stream>>>(ids, emb, pos, x);

    for (int l = 0; l < NLAYER; ++l) {
        const float* ipw_l = ipw + (size_t)l * 2 * DINNER * DMODEL;
        const float* cw_l = cw + (size_t)l * DINNER * 4;
        const float* cb_l = cb + (size_t)l * DINNER;
        const float* xpw_l = xpw + (size_t)l * XDBL_LD * DINNER;
        const float* dpw_l = dpw + (size_t)l * DINNER * DTRANK;
        const float* dpb_l = dpb + (size_t)l * DINNER;
        const float* Alog_l = Alog + (size_t)l * DINNER * NSTATE;
        const float* Dsk_l = Dsk + (size_t)l * DINNER;
        const float* opw_l = opw + (size_t)l * DMODEL * DINNER;

        // xz = x @ ipw^T : (1024,3072)
        gemm_k<0, 0><<<dim3(NTOK / BM, (2 * DINNER) / BN), 256, 0, stream>>>(
            x, DMODEL, ipw_l, DMODEL, xz, 2 * DINNER, NTOK, 2 * DINNER, DMODEL, nullptr);
        // xi = silu(causal_dwconv(xz[:, :1536]))
        conv_k<<<NTOK * DINNER / 256, 256, 0, stream>>>(xz, cw_l, cb_l, xi);
        // x_dbl = xi @ xpw^T : (1024,80)
        gemm_k<0, 0><<<dim3(NTOK / BM, (XDBL_LD + BN - 1) / BN), 256, 0, stream>>>(
            xi, DINNER, xpw_l, DINNER, xdbl, XDBL_LD, NTOK, XDBL_LD, DINNER, nullptr);
        // dt = softplus(x_dbl[:, :48] @ dpw^T + dpb) : (1024,1536)
        gemm_k<1, 0><<<dim3(NTOK / BM, DINNER / BN), 256, 0, stream>>>(
            xdbl, XDBL_LD, dpw_l, DTRANK, dtb, DINNER, NTOK, DINNER, DTRANK, dpb_l);
        // selective scan fused with +D*xi and *silu(z)
        scan_k<<<dim3(DINNER / 256, BATCH), 256, 0, stream>>>(
            dtb, xi, xdbl, xz, Alog_l, Dsk_l, yb);
        // x += yb @ opw^T
        gemm_k<0, 1><<<dim3(NTOK / BM, DMODEL / BN), 256, 0, stream>>>(
            yb, DINNER, opw_l, DINNER, x, DMODEL, NTOK, DMODEL, DINNER, nullptr);
    }

    rmsnorm_k<<<NTOK, 256, 0, stream>>>(x, nw, (float*)d_out);
}

// Round 2
// 852.758 us; speedup vs baseline: 3.1521x; 3.1521x over previous
//
#include <hip/hip_runtime.h>
#include <math.h>

#define TLEN 256
#define BATCH 4
#define DMODEL 768
#define DINNER 1536
#define NSTATE 16
#define DTRANK 48
#define NLAYER 4
#define XDBL_LD 80
#define NTOK (BATCH * TLEN)

typedef __bf16 bf16x8 __attribute__((ext_vector_type(8)));
typedef float f32x4 __attribute__((ext_vector_type(4)));

__device__ inline unsigned short f2b(float f) {
    union { float f; unsigned u; } v;
    v.f = f;
    unsigned r = (v.u + 0x7fffu + ((v.u >> 16) & 1u)) >> 16;  // RNE
    return (unsigned short)r;
}

// ---------------- embed ----------------
__global__ __launch_bounds__(256) void embed_k(const int* __restrict__ ids,
                                               const float* __restrict__ emb,
                                               const float* __restrict__ pos,
                                               float* __restrict__ x) {
    int idx = blockIdx.x * 256 + threadIdx.x;
    int d = idx % DMODEL;
    int bt = idx / DMODEL;
    int t = bt % TLEN;
    x[idx] = emb[(size_t)ids[bt] * DMODEL + d] + pos[t * DMODEL + d];
}

// ---------------- f32 -> bf16 convert (n % 4 == 0) ----------------
__global__ __launch_bounds__(256) void f2b_k(const float* __restrict__ in,
                                             unsigned short* __restrict__ out, int n) {
    int i = (blockIdx.x * 256 + threadIdx.x) * 4;
    if (i < n) {
        float4 v = *reinterpret_cast<const float4*>(in + i);
        ushort4 o;
        o.x = f2b(v.x); o.y = f2b(v.y); o.z = f2b(v.z); o.w = f2b(v.w);
        *reinterpret_cast<ushort4*>(out + i) = o;
    }
}

// zero-padded K convert: out[r][k<kin]=bf16(in[r][k]), else 0
__global__ __launch_bounds__(256) void f2b_pad_k(const float* __restrict__ in,
                                                 unsigned short* __restrict__ out,
                                                 int rows, int kin, int kout) {
    int idx = blockIdx.x * 256 + threadIdx.x;
    if (idx < rows * kout) {
        int r = idx / kout, k = idx % kout;
        out[idx] = (k < kin) ? f2b(in[(size_t)r * kin + k]) : 0;
    }
}

// ---------------- bf16 MFMA GEMM ----------------
// C[m,n] (+)= act(sum_k A[m,k]*Bw[n,k] + bias[n]); A,Bw bf16 row-major, C f32.
// tile 128x64, BK=64, 256 thr = 4 waves (2x2), wave tile 64x32.
#define GBM 128
#define GBN 64
#define GBK 64
#define LDP 72  // padded LDS row (elems)

template <int ACT, int ADDC, int NGUARD>
__global__ __launch_bounds__(256) void mgemm_k(const unsigned short* __restrict__ A, int lda,
                                               const unsigned short* __restrict__ Bw, int ldb,
                                               float* __restrict__ C, int ldc,
                                               int M, int N, int K,
                                               const float* __restrict__ bias) {
    __shared__ __align__(16) unsigned short Ab[GBM][LDP];
    __shared__ __align__(16) unsigned short Bb[GBN][LDP];
    int tid = threadIdx.x;
    int lane = tid & 63;
    int wave = tid >> 6;
    int wm = (wave >> 1) * 64;
    int wn = (wave & 1) * 32;
    int bm = blockIdx.x * GBM;
    int bn = blockIdx.y * GBN;
    int fr = lane & 15;
    int fk = (lane >> 4) * 8;

    int arow = tid >> 1, acol = (tid & 1) * 32;   // 32 elems (64B) per thread
    int brow = tid >> 2, bcol = (tid & 3) * 16;   // 16 elems (32B) per thread

    f32x4 acc[4][2] = {};

    for (int k0 = 0; k0 < K; k0 += GBK) {
        float4 av0, av1, av2, av3, bv0, bv1;
        {
            const float4* ap = reinterpret_cast<const float4*>(
                A + (size_t)(bm + arow) * lda + k0 + acol);
            av0 = ap[0]; av1 = ap[1]; av2 = ap[2]; av3 = ap[3];
        }
        {
            float4 z4 = {0.f, 0.f, 0.f, 0.f};
            bv0 = z4; bv1 = z4;
            if (!NGUARD || (bn + brow) < N) {
                const float4* bp = reinterpret_cast<const float4*>(
                    Bw + (size_t)(bn + brow) * ldb + k0 + bcol);
                bv0 = bp[0]; bv1 = bp[1];
            }
        }
        __syncthreads();
        {
            float4* aw = reinterpret_cast<float4*>(&Ab[arow][acol]);
            aw[0] = av0; aw[1] = av1; aw[2] = av2; aw[3] = av3;
            float4* bw = reinterpret_cast<float4*>(&Bb[brow][bcol]);
            bw[0] = bv0; bw[1] = bv1;
        }
        __syncthreads();
#pragma unroll
        for (int ks = 0; ks < 2; ++ks) {
            int kk = ks * 32 + fk;
            bf16x8 af[4], bf[2];
#pragma unroll
            for (int i = 0; i < 4; ++i)
                af[i] = *reinterpret_cast<const bf16x8*>(&Ab[wm + i * 16 + fr][kk]);
#pragma unroll
            for (int j = 0; j < 2; ++j)
                bf[j] = *reinterpret_cast<const bf16x8*>(&Bb[wn + j * 16 + fr][kk]);
#pragma unroll
            for (int i = 0; i < 4; ++i)
#pragma unroll
                for (int j = 0; j < 2; ++j)
                    acc[i][j] = __builtin_amdgcn_mfma_f32_16x16x32_bf16(
                        af[i], bf[j], acc[i][j], 0, 0, 0);
        }
    }

#pragma unroll
    for (int i = 0; i < 4; ++i) {
#pragma unroll
        for (int j = 0; j < 2; ++j) {
            int col = bn + wn + j * 16 + fr;
            if (NGUARD && col >= N) continue;
            float bv = (ACT == 1) ? bias[col] : 0.f;
#pragma unroll
            for (int q = 0; q < 4; ++q) {
                int row = bm + wm + i * 16 + (lane >> 4) * 4 + q;
                float v = acc[i][j][q];
                if (ACT == 1) {
                    v += bv;
                    v = (v > 0.f) ? v + log1pf(expf(-v)) : log1pf(expf(v));
                }
                size_t idx = (size_t)row * ldc + col;
                C[idx] = (ADDC ? C[idx] : 0.f) + v;
            }
        }
    }
}

// ---------------- causal depthwise conv (K=4) + bias + SiLU ----------------
__global__ __launch_bounds__(256) void conv_k(const float* __restrict__ xz,
                                              const float* __restrict__ cw,
                                              const float* __restrict__ cb,
                                              float* __restrict__ xi,
                                              unsigned short* __restrict__ xib) {
    int idx = blockIdx.x * 256 + threadIdx.x;
    int d = idx % DINNER;
    int bt = idx / DINNER;
    int t = bt % TLEN;
    int b = bt / TLEN;
    float s = cb[d];
#pragma unroll
    for (int k = 0; k < 4; ++k) {
        int tt = t + k - 3;
        if (tt >= 0) s += cw[d * 4 + k] * xz[(size_t)(b * TLEN + tt) * (2 * DINNER) + d];
    }
    float v = s / (1.f + expf(-s));
    xi[idx] = v;
    xib[idx] = f2b(v);
}

// ---------------- lane-parallel selective scan ----------------
// 16 lanes per (b,d) chain, one lane per state n. grid (96, 4), 256 thr.
__global__ __launch_bounds__(256) void scan_k(const float* __restrict__ dtb,
                                              const float* __restrict__ xi,
                                              const float* __restrict__ xdbl,
                                              const float* __restrict__ xz,
                                              const float* __restrict__ Alog,
                                              const float* __restrict__ Dsk,
                                              unsigned short* __restrict__ ybb) {
    int n = threadIdx.x & 15;
    int d = blockIdx.x * 16 + (threadIdx.x >> 4);
    int b = blockIdx.y;
    float a = -expf(Alog[(size_t)d * NSTATE + n]);
    float Dv = Dsk[d];
    float h = 0.f;
    size_t row = (size_t)b * TLEN;
    float dtv = dtb[row * DINNER + d];
    float xiv = xi[row * DINNER + d];
    float Bn = xdbl[row * XDBL_LD + DTRANK + n];
    float Cn = xdbl[row * XDBL_LD + DTRANK + NSTATE + n];
    float zv = xz[row * (2 * DINNER) + DINNER + d];
    for (int t = 0; t < TLEN; ++t) {
        float dt2 = 0.f, xi2 = 0.f, B2 = 0.f, C2 = 0.f, z2 = 0.f;
        if (t + 1 < TLEN) {
            size_t r2 = row + 1;
            dt2 = dtb[r2 * DINNER + d];
            xi2 = xi[r2 * DINNER + d];
            B2 = xdbl[r2 * XDBL_LD + DTRANK + n];
            C2 = xdbl[r2 * XDBL_LD + DTRANK + NSTATE + n];
            z2 = xz[r2 * (2 * DINNER) + DINNER + d];
        }
        float dA = expf(dtv * a);
        h = dA * h + (dtv * xiv) * Bn;
        float p = h * Cn;
        p += __shfl_xor(p, 1);
        p += __shfl_xor(p, 2);
        p += __shfl_xor(p, 4);
        p += __shfl_xor(p, 8);
        if (n == 0) {
            float y = p + Dv * xiv;
            y *= zv / (1.f + expf(-zv));
            ybb[row * DINNER + d] = f2b(y);
        }
        dtv = dt2; xiv = xi2; Bn = B2; Cn = C2; zv = z2;
        ++row;
    }
}

// ---------------- RMSNorm ----------------
__global__ __launch_bounds__(256) void rmsnorm_k(const float* __restrict__ x,
                                                 const float* __restrict__ nw,
                                                 float* __restrict__ out) {
    int row = blockIdx.x;
    const float* xr = x + (size_t)row * DMODEL;
    int tid = threadIdx.x;
    float s = 0.f;
    for (int d = tid; d < DMODEL; d += 256) {
        float v = xr[d];
        s += v * v;
    }
#pragma unroll
    for (int off = 32; off >= 1; off >>= 1) s += __shfl_down(s, off);
    __shared__ float red[4];
    __shared__ float scale;
    int wid = tid >> 6, lane = tid & 63;
    if (lane == 0) red[wid] = s;
    __syncthreads();
    if (tid == 0) {
        float tot = red[0] + red[1] + red[2] + red[3];
        scale = rsqrtf(tot / (float)DMODEL + 1e-5f);
    }
    __syncthreads();
    float sc = scale;
    for (int d = tid; d < DMODEL; d += 256)
        out[(size_t)row * DMODEL + d] = xr[d] * sc * nw[d];
}

extern "C" void kernel_launch(void* const* d_in, const int* in_sizes, int n_in,
                              void* d_out, int out_size, void* d_ws, size_t ws_size,
                              hipStream_t stream) {
    const int* ids = (const int*)d_in[0];
    const float* emb = (const float*)d_in[1];
    const float* pos = (const float*)d_in[2];
    const float* ipw = (const float*)d_in[3];
    const float* cw = (const float*)d_in[4];
    const float* cb = (const float*)d_in[5];
    const float* xpw = (const float*)d_in[6];
    const float* dpw = (const float*)d_in[7];
    const float* dpb = (const float*)d_in[8];
    const float* Alog = (const float*)d_in[9];
    const float* Dsk = (const float*)d_in[10];
    const float* opw = (const float*)d_in[11];
    const float* nw = (const float*)d_in[12];

    // f32 scratch
    float* x = (float*)d_ws;                        // 786432
    float* xz = x + 786432;                         // 3145728
    float* xi = xz + 3145728;                       // 1572864
    float* xdbl = xi + 1572864;                     // 81920
    float* dtb = xdbl + 81920;                      // 1572864
    // bf16 scratch
    unsigned short* bf = (unsigned short*)(dtb + 1572864);
    unsigned short* xb = bf;                        // 786432
    unsigned short* xib = xb + 786432;              // 1572864
    unsigned short* ybb = xib + 1572864;            // 1572864
    unsigned short* xdblb = ybb + 1572864;          // 81920
    unsigned short* w_ip = xdblb + 81920;           // 2359296
    unsigned short* w_op = w_ip + 2359296;          // 1179648
    unsigned short* w_xp = w_op + 1179648;          // 122880
    unsigned short* w_dt = w_xp + 122880;           // 98304

    embed_k<<<NTOK * DMODEL / 256, 256, 0, stream>>>(ids, emb, pos, x);

    for (int l = 0; l < NLAYER; ++l) {
        const float* ipw_l = ipw + (size_t)l * 2 * DINNER * DMODEL;
        const float* cw_l = cw + (size_t)l * DINNER * 4;
        const float* cb_l = cb + (size_t)l * DINNER;
        const float* xpw_l = xpw + (size_t)l * XDBL_LD * DINNER;
        const float* dpw_l = dpw + (size_t)l * DINNER * DTRANK;
        const float* dpb_l = dpb + (size_t)l * DINNER;
        const float* Alog_l = Alog + (size_t)l * DINNER * NSTATE;
        const float* Dsk_l = Dsk + (size_t)l * DINNER;
        const float* opw_l = opw + (size_t)l * DMODEL * DINNER;

        // weight + activation converts
        f2b_k<<<2359296 / 1024, 256, 0, stream>>>(ipw_l, w_ip, 2359296);
        f2b_k<<<1179648 / 1024, 256, 0, stream>>>(opw_l, w_op, 1179648);
        f2b_k<<<122880 / 1024, 256, 0, stream>>>(xpw_l, w_xp, 122880);
        f2b_pad_k<<<(1536 * 64) / 256, 256, 0, stream>>>(dpw_l, w_dt, 1536, DTRANK, 64);
        f2b_k<<<786432 / 1024, 256, 0, stream>>>(x, xb, 786432);

        // xz = x @ ipw^T : (1024, 3072)
        mgemm_k<0, 0, 0><<<dim3(NTOK / GBM, 3072 / GBN), 256, 0, stream>>>(
            xb, DMODEL, w_ip, DMODEL, xz, 2 * DINNER, NTOK, 2 * DINNER, DMODEL, nullptr);
        // xi = silu(causal_dwconv(xz[:, :1536]))  (+ bf16 copy)
        conv_k<<<NTOK * DINNER / 256, 256, 0, stream>>>(xz, cw_l, cb_l, xi, xib);
        // x_dbl = xi @ xpw^T : (1024, 80)
        mgemm_k<0, 0, 1><<<dim3(NTOK / GBM, 2), 256, 0, stream>>>(
            xib, DINNER, w_xp, DINNER, xdbl, XDBL_LD, NTOK, XDBL_LD, DINNER, nullptr);
        f2b_k<<<81920 / 1024, 256, 0, stream>>>(xdbl, xdblb, 81920);
        // dt = softplus(x_dbl[:, :48] @ dpw^T + dpb)  (K zero-padded to 64)
        mgemm_k<1, 0, 0><<<dim3(NTOK / GBM, DINNER / GBN), 256, 0, stream>>>(
            xdblb, XDBL_LD, w_dt, 64, dtb, DINNER, NTOK, DINNER, 64, dpb_l);
        // selective scan fused with +D*xi and *silu(z); writes bf16 y
        scan_k<<<dim3(DINNER / 16, BATCH), 256, 0, stream>>>(
            dtb, xi, xdbl, xz, Alog_l, Dsk_l, ybb);
        // x += y @ opw^T
        mgemm_k<0, 1, 0><<<dim3(NTOK / GBM, DMODEL / GBN), 256, 0, stream>>>(
            ybb, DINNER, w_op, DINNER, x, DMODEL, NTOK, DMODEL, DINNER, nullptr);
    }

    rmsnorm_k<<<NTOK, 256, 0, stream>>>(x, nw, (float*)d_out);
}

// Round 3
// 823.284 us; speedup vs baseline: 3.2650x; 1.0358x over previous
//
#include <hip/hip_runtime.h>
#include <math.h>

#define TLEN 256
#define BATCH 4
#define DMODEL 768
#define DINNER 1536
#define NSTATE 16
#define DTRANK 48
#define NLAYER 4
#define NTOK (BATCH * TLEN)

typedef __bf16 bf16x8 __attribute__((ext_vector_type(8)));
typedef float f32x4 __attribute__((ext_vector_type(4)));

__device__ inline unsigned short f2b(float f) {
    union { float f; unsigned u; } v;
    v.f = f;
    unsigned r = (v.u + 0x7fffu + ((v.u >> 16) & 1u)) >> 16;  // RNE
    return (unsigned short)r;
}

// ---------------- embed ----------------
__global__ __launch_bounds__(256) void embed_k(const int* __restrict__ ids,
                                               const float* __restrict__ emb,
                                               const float* __restrict__ pos,
                                               float* __restrict__ x) {
    int idx = blockIdx.x * 256 + threadIdx.x;
    int d = idx % DMODEL;
    int bt = idx / DMODEL;
    int t = bt % TLEN;
    x[idx] = emb[(size_t)ids[bt] * DMODEL + d] + pos[t * DMODEL + d];
}

// ---------------- fused per-layer weight convert ----------------
#define S_IP 2359296
#define S_OP 1179648
#define S_XP 122880
#define S_DT 98304
__global__ __launch_bounds__(256) void wconv_k(const float* __restrict__ ipw,
                                               const float* __restrict__ opw,
                                               const float* __restrict__ xpw,
                                               const float* __restrict__ dpw,
                                               unsigned short* __restrict__ w_ip,
                                               unsigned short* __restrict__ w_op,
                                               unsigned short* __restrict__ w_xp,
                                               unsigned short* __restrict__ w_dt) {
    int i4 = (blockIdx.x * 256 + threadIdx.x) * 4;
    if (i4 < S_IP) {
        float4 v = *(const float4*)(ipw + i4);
        ushort4 o; o.x = f2b(v.x); o.y = f2b(v.y); o.z = f2b(v.z); o.w = f2b(v.w);
        *(ushort4*)(w_ip + i4) = o;
    } else if (i4 < S_IP + S_OP) {
        int i = i4 - S_IP;
        float4 v = *(const float4*)(opw + i);
        ushort4 o; o.x = f2b(v.x); o.y = f2b(v.y); o.z = f2b(v.z); o.w = f2b(v.w);
        *(ushort4*)(w_op + i) = o;
    } else if (i4 < S_IP + S_OP + S_XP) {
        int i = i4 - S_IP - S_OP;
        float4 v = *(const float4*)(xpw + i);
        ushort4 o; o.x = f2b(v.x); o.y = f2b(v.y); o.z = f2b(v.z); o.w = f2b(v.w);
        *(ushort4*)(w_xp + i) = o;
    } else if (i4 < S_IP + S_OP + S_XP + S_DT) {
        int o0 = i4 - S_IP - S_OP - S_XP;
#pragma unroll
        for (int u = 0; u < 4; ++u) {
            int oi = o0 + u;
            int r = oi >> 6, k = oi & 63;
            w_dt[oi] = (k < DTRANK) ? f2b(dpw[r * DTRANK + k]) : 0;
        }
    }
}

// ---------------- bf16 MFMA GEMM, templated tile + epilogue mode ----------------
// C[m,n] = sum_k A[m,k]*Bw[n,k]  (A,Bw row-major, k contiguous)
// MODE 0: o0 = xzT [N][1024] f32 transposed store            (in_proj)
// MODE 1: o1 = xdblb bf16 [1024][64] (cols<48, 48..63 zero); o2 = BCt [32][1024] f32 (x_proj)
// MODE 2: o0 = dtT [N][1024] f32 transposed, softplus(v+bias[col])  (dt_proj)
// MODE 3: o0 = x [1024][N] f32, accumulate (+=)              (out_proj)
#define LDP 72
template <int BM, int MODE, int NGUARD, int AF32>
__global__ __launch_bounds__(256) void mgemm_k(const void* __restrict__ Av, int lda,
                                               const unsigned short* __restrict__ Bw, int ldb,
                                               int M, int N, int K,
                                               const float* __restrict__ bias,
                                               float* __restrict__ o0,
                                               unsigned short* __restrict__ o1,
                                               float* __restrict__ o2) {
    constexpr int MI = BM / 32;
    __shared__ __align__(16) unsigned short Ab[BM][LDP];
    __shared__ __align__(16) unsigned short Bb[64][LDP];
    const unsigned short* A16 = (const unsigned short*)Av;
    const float* A32 = (const float*)Av;
    int tid = threadIdx.x;
    int lane = tid & 63;
    int wave = tid >> 6;
    int wm = (wave >> 1) * (BM / 2);
    int wn = (wave & 1) * 32;
    int bm = blockIdx.x * BM;
    int bn = blockIdx.y * 64;
    int fr = lane & 15;
    int fk = (lane >> 4) * 8;

    f32x4 acc[MI][2] = {};

    for (int k0 = 0; k0 < K; k0 += 64) {
        __syncthreads();
#pragma unroll
        for (int c = 0; c < BM / 32; ++c) {
            int id = c * 256 + tid;
            int row = id >> 3, col = (id & 7) * 8;
            if (AF32) {
                const float* src = A32 + (size_t)(bm + row) * lda + k0 + col;
                float4 v0 = *(const float4*)src;
                float4 v1 = *(const float4*)(src + 4);
                ushort4 p0, p1;
                p0.x = f2b(v0.x); p0.y = f2b(v0.y); p0.z = f2b(v0.z); p0.w = f2b(v0.w);
                p1.x = f2b(v1.x); p1.y = f2b(v1.y); p1.z = f2b(v1.z); p1.w = f2b(v1.w);
                *(ushort4*)&Ab[row][col] = p0;
                *(ushort4*)&Ab[row][col + 4] = p1;
            } else {
                const unsigned short* src = A16 + (size_t)(bm + row) * lda + k0 + col;
                *(ushort4*)&Ab[row][col] = *(const ushort4*)src;
                *(ushort4*)&Ab[row][col + 4] = *(const ushort4*)(src + 4);
            }
        }
#pragma unroll
        for (int c = 0; c < 2; ++c) {
            int id = c * 256 + tid;
            int row = id >> 3, col = (id & 7) * 8;
            ushort4 v0 = {0, 0, 0, 0}, v1 = {0, 0, 0, 0};
            if (!NGUARD || bn + row < N) {
                const unsigned short* src = Bw + (size_t)(bn + row) * ldb + k0 + col;
                v0 = *(const ushort4*)src;
                v1 = *(const ushort4*)(src + 4);
            }
            *(ushort4*)&Bb[row][col] = v0;
            *(ushort4*)&Bb[row][col + 4] = v1;
        }
        __syncthreads();
#pragma unroll
        for (int ks = 0; ks < 2; ++ks) {
            int kk = ks * 32 + fk;
            bf16x8 af[MI], bfr[2];
#pragma unroll
            for (int i = 0; i < MI; ++i)
                af[i] = *(const bf16x8*)&Ab[wm + i * 16 + fr][kk];
#pragma unroll
            for (int j = 0; j < 2; ++j)
                bfr[j] = *(const bf16x8*)&Bb[wn + j * 16 + fr][kk];
#pragma unroll
            for (int i = 0; i < MI; ++i)
#pragma unroll
                for (int j = 0; j < 2; ++j)
                    acc[i][j] = __builtin_amdgcn_mfma_f32_16x16x32_bf16(
                        af[i], bfr[j], acc[i][j], 0, 0, 0);
        }
    }

#pragma unroll
    for (int i = 0; i < MI; ++i) {
#pragma unroll
        for (int j = 0; j < 2; ++j) {
            int col = bn + wn + j * 16 + fr;
            if (NGUARD && col >= N) continue;
            int row0 = bm + wm + i * 16 + (lane >> 4) * 4;
            if (MODE == 0) {
                float4 r;
                r.x = acc[i][j][0]; r.y = acc[i][j][1]; r.z = acc[i][j][2]; r.w = acc[i][j][3];
                *(float4*)(o0 + (size_t)col * NTOK + row0) = r;
            } else if (MODE == 2) {
                float bv = bias[col];
                float4 r;
#pragma unroll
                for (int q = 0; q < 4; ++q) {
                    float v = acc[i][j][q] + bv;
                    v = (v > 0.f) ? v + log1pf(__expf(-v)) : log1pf(__expf(v));
                    ((float*)&r)[q] = v;
                }
                *(float4*)(o0 + (size_t)col * NTOK + row0) = r;
            } else if (MODE == 1) {
#pragma unroll
                for (int q = 0; q < 4; ++q) {
                    int r = row0 + q;
                    float v = acc[i][j][q];
                    if (col < DTRANK) {
                        o1[r * 64 + col] = f2b(v);
                    } else {
                        if (col < 64) o1[r * 64 + col] = 0;
                        o2[(size_t)(col - DTRANK) * NTOK + r] = v;
                    }
                }
            } else {  // MODE 3: residual accumulate
#pragma unroll
                for (int q = 0; q < 4; ++q) {
                    int r = row0 + q;
                    o0[(size_t)r * N + col] += acc[i][j][q];
                }
            }
        }
    }
}

// ---------------- causal dwconv(K=4) + bias + SiLU, transposed layout ----------------
// reads xzT rows 0..1535 (x-part), writes xiT [d][1024] f32 + xib [tok][1536] bf16
__global__ __launch_bounds__(256) void conv_k(const float* __restrict__ xzT,
                                              const float* __restrict__ cw,
                                              const float* __restrict__ cb,
                                              float* __restrict__ xiT,
                                              unsigned short* __restrict__ xib) {
    int tid = threadIdx.x;
    int d = blockIdx.x * 4 + (tid >> 6);
    int b = blockIdx.y;
    int t0 = (tid & 63) * 4;
    const float* src = xzT + (size_t)d * NTOK + b * TLEN + t0;
    float4 cur = *(const float4*)src;
    float4 prev = {0.f, 0.f, 0.f, 0.f};
    if (t0 > 0) prev = *(const float4*)(src - 4);
    float w0 = cw[d * 4 + 0], w1 = cw[d * 4 + 1], w2 = cw[d * 4 + 2], w3 = cw[d * 4 + 3];
    float bb = cb[d];
    float xw[8] = {prev.x, prev.y, prev.z, prev.w, cur.x, cur.y, cur.z, cur.w};
    float4 r;
#pragma unroll
    for (int u = 0; u < 4; ++u) {
        float s = bb + w0 * xw[u + 1] + w1 * xw[u + 2] + w2 * xw[u + 3] + w3 * xw[u + 4];
        float v = s / (1.f + __expf(-s));
        ((float*)&r)[u] = v;
        xib[(size_t)(b * TLEN + t0 + u) * DINNER + d] = f2b(v);
    }
    *(float4*)(xiT + (size_t)d * NTOK + b * TLEN + t0) = r;
}

// ---------------- time-chunked lane-parallel selective scan ----------------
// block: 4 waves = 4 time-chunks; wave: 4 chains (consecutive d) x 16 states.
// grid (DINNER/4 = 384, BATCH)
__global__ __launch_bounds__(256) void scan_k(const float* __restrict__ dtT,
                                              const float* __restrict__ xiT,
                                              const float* __restrict__ xzT,
                                              const float* __restrict__ BCt,
                                              const float* __restrict__ Alog,
                                              const float* __restrict__ Dsk,
                                              unsigned short* __restrict__ ybb) {
    __shared__ float yl[4][260];
    __shared__ float cum[4][260];
    __shared__ float hL[4][4][16];
    __shared__ float Pb[4][4][16];
    __shared__ float Hin[4][4][16];

    int tid = threadIdx.x;
    int c = tid >> 6;
    int lane = tid & 63;
    int ch = lane >> 4;
    int n = lane & 15;
    int d = blockIdx.x * 4 + ch;
    int b = blockIdx.y;
    int tl0 = c * 64;

    float a = -__expf(Alog[d * NSTATE + n]);
    const float* dtp = dtT + (size_t)d * NTOK + b * TLEN + tl0;
    const float* xip = xiT + (size_t)d * NTOK + b * TLEN + tl0;
    const float* Bp = BCt + (size_t)n * NTOK + b * TLEN + tl0;
    const float* Cp = BCt + (size_t)(NSTATE + n) * NTOK + b * TLEN + tl0;

    float h = 0.f, cd = 0.f;
    for (int t8 = 0; t8 < 64; t8 += 8) {
        float4 d0 = *(const float4*)(dtp + t8), d1 = *(const float4*)(dtp + t8 + 4);
        float4 x0 = *(const float4*)(xip + t8), x1 = *(const float4*)(xip + t8 + 4);
        float4 B0 = *(const float4*)(Bp + t8), B1 = *(const float4*)(Bp + t8 + 4);
        float4 C0 = *(const float4*)(Cp + t8), C1 = *(const float4*)(Cp + t8 + 4);
        float dts[8] = {d0.x, d0.y, d0.z, d0.w, d1.x, d1.y, d1.z, d1.w};
        float xis[8] = {x0.x, x0.y, x0.z, x0.w, x1.x, x1.y, x1.z, x1.w};
        float Bs[8] = {B0.x, B0.y, B0.z, B0.w, B1.x, B1.y, B1.z, B1.w};
        float Cs[8] = {C0.x, C0.y, C0.z, C0.w, C1.x, C1.y, C1.z, C1.w};
#pragma unroll
        for (int u = 0; u < 8; ++u) {
            cd += dts[u];
            float dA = __expf(dts[u] * a);
            h = dA * h + (dts[u] * xis[u]) * Bs[u];
            float p = h * Cs[u];
            p += __shfl_xor(p, 1);
            p += __shfl_xor(p, 2);
            p += __shfl_xor(p, 4);
            p += __shfl_xor(p, 8);
            if (n == 0) {
                yl[ch][tl0 + t8 + u] = p;
                cum[ch][tl0 + t8 + u] = cd;
            }
        }
    }
    hL[c][ch][n] = h;
    Pb[c][ch][n] = __expf(a * cd);
    __syncthreads();
    if (c == 0) {
        float H = 0.f;
        Hin[0][ch][n] = 0.f;
#pragma unroll
        for (int cc = 1; cc < 4; ++cc) {
            H = Pb[cc - 1][ch][n] * H + hL[cc - 1][ch][n];
            Hin[cc][ch][n] = H;
        }
    }
    __syncthreads();
    float Hv = Hin[c][ch][n];
    float Dv = Dsk[d];
    const float* zp = xzT + (size_t)(DINNER + d) * NTOK + b * TLEN + tl0;
    for (int t8 = 0; t8 < 64; t8 += 8) {
        float4 C0 = *(const float4*)(Cp + t8), C1 = *(const float4*)(Cp + t8 + 4);
        float4 x0 = *(const float4*)(xip + t8), x1 = *(const float4*)(xip + t8 + 4);
        float4 z0 = *(const float4*)(zp + t8), z1 = *(const float4*)(zp + t8 + 4);
        float Cs[8] = {C0.x, C0.y, C0.z, C0.w, C1.x, C1.y, C1.z, C1.w};
        float xis[8] = {x0.x, x0.y, x0.z, x0.w, x1.x, x1.y, x1.z, x1.w};
        float zs[8] = {z0.x, z0.y, z0.z, z0.w, z1.x, z1.y, z1.z, z1.w};
#pragma unroll
        for (int u = 0; u < 8; ++u) {
            float cdt = cum[ch][tl0 + t8 + u];
            float corr = Cs[u] * __expf(a * cdt) * Hv;
            corr += __shfl_xor(corr, 1);
            corr += __shfl_xor(corr, 2);
            corr += __shfl_xor(corr, 4);
            corr += __shfl_xor(corr, 8);
            if (n == 0) {
                float y = yl[ch][tl0 + t8 + u] + corr + Dv * xis[u];
                float zz = zs[u];
                y *= zz / (1.f + __expf(-zz));
                yl[ch][tl0 + t8 + u] = y;
            }
        }
    }
    __syncthreads();
    {
        int t = tid;
        ushort4 o;
        o.x = f2b(yl[0][t]);
        o.y = f2b(yl[1][t]);
        o.z = f2b(yl[2][t]);
        o.w = f2b(yl[3][t]);
        *(ushort4*)(ybb + (size_t)(b * TLEN + t) * DINNER + blockIdx.x * 4) = o;
    }
}

// ---------------- RMSNorm ----------------
__global__ __launch_bounds__(256) void rmsnorm_k(const float* __restrict__ x,
                                                 const float* __restrict__ nw,
                                                 float* __restrict__ out) {
    int row = blockIdx.x;
    const float* xr = x + (size_t)row * DMODEL;
    int tid = threadIdx.x;
    float s = 0.f;
    for (int d = tid; d < DMODEL; d += 256) {
        float v = xr[d];
        s += v * v;
    }
#pragma unroll
    for (int off = 32; off >= 1; off >>= 1) s += __shfl_down(s, off);
    __shared__ float red[4];
    __shared__ float scale;
    int wid = tid >> 6, lane = tid & 63;
    if (lane == 0) red[wid] = s;
    __syncthreads();
    if (tid == 0) {
        float tot = red[0] + red[1] + red[2] + red[3];
        scale = rsqrtf(tot / (float)DMODEL + 1e-5f);
    }
    __syncthreads();
    float sc = scale;
    for (int d = tid; d < DMODEL; d += 256)
        out[(size_t)row * DMODEL + d] = xr[d] * sc * nw[d];
}

extern "C" void kernel_launch(void* const* d_in, const int* in_sizes, int n_in,
                              void* d_out, int out_size, void* d_ws, size_t ws_size,
                              hipStream_t stream) {
    const int* ids = (const int*)d_in[0];
    const float* emb = (const float*)d_in[1];
    const float* pos = (const float*)d_in[2];
    const float* ipw = (const float*)d_in[3];
    const float* cw = (const float*)d_in[4];
    const float* cb = (const float*)d_in[5];
    const float* xpw = (const float*)d_in[6];
    const float* dpw = (const float*)d_in[7];
    const float* dpb = (const float*)d_in[8];
    const float* Alog = (const float*)d_in[9];
    const float* Dsk = (const float*)d_in[10];
    const float* opw = (const float*)d_in[11];
    const float* nw = (const float*)d_in[12];

    float* x = (float*)d_ws;                   // 786432
    float* xzT = x + 786432;                   // 3145728
    float* xiT = xzT + 3145728;                // 1572864
    float* dtT = xiT + 1572864;                // 1572864
    float* BCt = dtT + 1572864;                // 32768
    unsigned short* xib = (unsigned short*)(BCt + 32768);  // 1572864
    unsigned short* ybb = xib + 1572864;       // 1572864
    unsigned short* xdblb = ybb + 1572864;     // 65536
    unsigned short* w_ip = xdblb + 65536;      // 2359296
    unsigned short* w_op = w_ip + S_IP;        // 1179648
    unsigned short* w_xp = w_op + S_OP;        // 122880
    unsigned short* w_dt = w_xp + S_XP;        // 98304

    embed_k<<<NTOK * DMODEL / 256, 256, 0, stream>>>(ids, emb, pos, x);

    for (int l = 0; l < NLAYER; ++l) {
        const float* ipw_l = ipw + (size_t)l * S_IP;
        const float* cw_l = cw + (size_t)l * DINNER * 4;
        const float* cb_l = cb + (size_t)l * DINNER;
        const float* xpw_l = xpw + (size_t)l * S_XP;
        const float* dpw_l = dpw + (size_t)l * DINNER * DTRANK;
        const float* dpb_l = dpb + (size_t)l * DINNER;
        const float* Alog_l = Alog + (size_t)l * DINNER * NSTATE;
        const float* Dsk_l = Dsk + (size_t)l * DINNER;
        const float* opw_l = opw + (size_t)l * S_OP;

        wconv_k<<<(S_IP + S_OP + S_XP + S_DT) / 1024, 256, 0, stream>>>(
            ipw_l, opw_l, xpw_l, dpw_l, w_ip, w_op, w_xp, w_dt);

        // xzT[e][tok] = (x @ ipw^T)^T
        mgemm_k<128, 0, 0, 1><<<dim3(NTOK / 128, 3072 / 64), 256, 0, stream>>>(
            (const void*)x, DMODEL, w_ip, DMODEL, NTOK, 3072, DMODEL, nullptr,
            xzT, nullptr, nullptr);
        // conv + silu
        conv_k<<<dim3(DINNER / 4, BATCH), 256, 0, stream>>>(xzT, cw_l, cb_l, xiT, xib);
        // x_dbl: bf16 dt-part [tok][64] + BCt [32][tok] f32
        mgemm_k<128, 1, 1, 0><<<dim3(NTOK / 128, 2), 256, 0, stream>>>(
            (const void*)xib, DINNER, w_xp, DINNER, NTOK, 80, DINNER, nullptr,
            nullptr, xdblb, BCt);
        // dtT[d][tok] = softplus(x_dbl[:, :48] @ dpw^T + dpb)^T
        mgemm_k<128, 2, 0, 0><<<dim3(NTOK / 128, DINNER / 64), 256, 0, stream>>>(
            (const void*)xdblb, 64, w_dt, 64, NTOK, DINNER, 64, dpb_l,
            dtT, nullptr, nullptr);
        // scan
        scan_k<<<dim3(DINNER / 4, BATCH), 256, 0, stream>>>(
            dtT, xiT, xzT, BCt, Alog_l, Dsk_l, ybb);
        // x += y @ opw^T
        mgemm_k<64, 3, 0, 0><<<dim3(NTOK / 64, DMODEL / 64), 256, 0, stream>>>(
            (const void*)ybb, DINNER, w_op, DINNER, NTOK, DMODEL, DINNER, nullptr,
            x, nullptr, nullptr);
    }

    rmsnorm_k<<<NTOK, 256, 0, stream>>>(x, nw, (float*)d_out);
}

// Round 4
// 650.688 us; speedup vs baseline: 4.1310x; 1.2653x over previous
//
#include <hip/hip_runtime.h>
#include <math.h>

#define TLEN 256
#define BATCH 4
#define DMODEL 768
#define DINNER 1536
#define NSTATE 16
#define DTRANK 48
#define NLAYER 4
#define NTOK 1024

#define S_IP 2359296
#define S_OP 1179648
#define S_XP2 196608   /* 128 x 1536 zero-padded */
#define S_DT 98304     /* 1536 x 64 zero-padded */

typedef __bf16 bf16x8 __attribute__((ext_vector_type(8)));
typedef float f32x4 __attribute__((ext_vector_type(4)));

__device__ inline unsigned short f2b(float f) {
    union { float f; unsigned u; } v;
    v.f = f;
    unsigned r = (v.u + 0x7fffu + ((v.u >> 16) & 1u)) >> 16;  // RNE
    return (unsigned short)r;
}

__device__ inline void gload16(const void* g, void* l) {
    __builtin_amdgcn_global_load_lds(
        (const __attribute__((address_space(1))) void*)g,
        (__attribute__((address_space(3))) void*)l, 16, 0, 0);
}

// ---------------- embed: f32 x + bf16 xb ----------------
__global__ __launch_bounds__(256) void embed_k(const int* __restrict__ ids,
                                               const float* __restrict__ emb,
                                               const float* __restrict__ pos,
                                               float* __restrict__ x,
                                               unsigned short* __restrict__ xb) {
    int idx = blockIdx.x * 256 + threadIdx.x;
    int d = idx % DMODEL;
    int bt = idx / DMODEL;
    int t = bt % TLEN;
    float v = emb[(size_t)ids[bt] * DMODEL + d] + pos[t * DMODEL + d];
    x[idx] = v;
    xb[idx] = f2b(v);
}

// ---------------- fused per-layer weight convert (with padding) ----------------
__global__ __launch_bounds__(256) void wconv_k(const float* __restrict__ ipw,
                                               const float* __restrict__ opw,
                                               const float* __restrict__ xpw,
                                               const float* __restrict__ dpw,
                                               unsigned short* __restrict__ w_ip,
                                               unsigned short* __restrict__ w_op,
                                               unsigned short* __restrict__ w_xp,
                                               unsigned short* __restrict__ w_dt) {
    int i4 = (blockIdx.x * 256 + threadIdx.x) * 4;
    if (i4 < S_IP) {
        float4 v = *(const float4*)(ipw + i4);
        ushort4 o; o.x = f2b(v.x); o.y = f2b(v.y); o.z = f2b(v.z); o.w = f2b(v.w);
        *(ushort4*)(w_ip + i4) = o;
    } else if (i4 < S_IP + S_OP) {
        int i = i4 - S_IP;
        float4 v = *(const float4*)(opw + i);
        ushort4 o; o.x = f2b(v.x); o.y = f2b(v.y); o.z = f2b(v.z); o.w = f2b(v.w);
        *(ushort4*)(w_op + i) = o;
    } else if (i4 < S_IP + S_OP + S_XP2) {
        int i = i4 - S_IP - S_OP;
        int r = i / 1536, k = i % 1536;
        ushort4 o = {0, 0, 0, 0};
        if (r < 80) {
            float4 v = *(const float4*)(xpw + (size_t)r * 1536 + k);
            o.x = f2b(v.x); o.y = f2b(v.y); o.z = f2b(v.z); o.w = f2b(v.w);
        }
        *(ushort4*)(w_xp + i) = o;
    } else if (i4 < S_IP + S_OP + S_XP2 + S_DT) {
        int i = i4 - S_IP - S_OP - S_XP2;
        int r = i >> 6, k = i & 63;
        ushort4 o = {0, 0, 0, 0};
        if (k < DTRANK) {
            float4 v = *(const float4*)(dpw + (size_t)r * DTRANK + k);
            o.x = f2b(v.x); o.y = f2b(v.y); o.z = f2b(v.z); o.w = f2b(v.w);
        }
        *(ushort4*)(w_dt + i) = o;
    }
}

// ---------------- bf16 MFMA GEMM with global_load_lds staging ----------------
// D[row][col] = sum_k A[row,k]*B[col,k]; A,B bf16 row-major (k contiguous).
// MODE 0: rows=e, cols=tok -> o0 = xzT [3072][1024] f32                (in_proj)
// MODE 1: rows=feat(pad128), cols=tok -> o2 = BCt [32][1024] f32,
//         o1 = xdblb bf16 [1024][64] via LDS transpose (bm==0 only)    (x_proj)
// MODE 2: rows=d, cols=tok -> o0 = dtT [1536][1024] f32, softplus(v + bias[row]) (dt_proj)
// MODE 3: rows=tok, cols=d -> o0 = x [1024][768] f32 +=, o1 = xb bf16  (out_proj)
template <int BM, int MODE>
__global__ __launch_bounds__(256) void mgemm_k(const unsigned short* __restrict__ A, int lda,
                                               const unsigned short* __restrict__ B, int ldb,
                                               int K,
                                               const float* __restrict__ bias,
                                               float* __restrict__ o0,
                                               unsigned short* __restrict__ o1,
                                               float* __restrict__ o2) {
    constexpr int MI = BM / 32;
    __shared__ __align__(16) unsigned short Ab[BM * 64];
    __shared__ __align__(16) unsigned short Bb[64 * 64];
    __shared__ float Tt[(MODE == 1) ? 64 * 64 : 1];

    int tid = threadIdx.x;
    int lane = tid & 63;
    int wave = tid >> 6;
    int wm = (wave >> 1) * (BM / 2);
    int wn = (wave & 1) * 32;
    int bm = blockIdx.x * BM;
    int bn = blockIdx.y * 64;
    int fr = lane & 15;
    int fq = lane >> 4;
    int fk = fq * 8;
    int srow = lane >> 3;        // 0..7
    int scol = (lane & 7) * 8;   // 0..56

    f32x4 acc[MI][2] = {};

    for (int k0 = 0; k0 < K; k0 += 64) {
        __syncthreads();
#pragma unroll
        for (int c = 0; c < BM / 32; ++c) {   // A: BM/4 rows per wave, 8 rows/call
            int r = wave * (BM / 4) + c * 8;
            gload16(A + (size_t)(bm + r + srow) * lda + k0 + scol, &Ab[r * 64]);
        }
#pragma unroll
        for (int c = 0; c < 2; ++c) {         // B: 16 rows per wave
            int r = wave * 16 + c * 8;
            gload16(B + (size_t)(bn + r + srow) * ldb + k0 + scol, &Bb[r * 64]);
        }
        __syncthreads();
#pragma unroll
        for (int ks = 0; ks < 2; ++ks) {
            int kk = ks * 32 + fk;
            bf16x8 af[MI], bfr[2];
#pragma unroll
            for (int i = 0; i < MI; ++i)
                af[i] = *(const bf16x8*)&Ab[(wm + i * 16 + fr) * 64 + kk];
#pragma unroll
            for (int j = 0; j < 2; ++j)
                bfr[j] = *(const bf16x8*)&Bb[(wn + j * 16 + fr) * 64 + kk];
#pragma unroll
            for (int i = 0; i < MI; ++i)
#pragma unroll
                for (int j = 0; j < 2; ++j)
                    acc[i][j] = __builtin_amdgcn_mfma_f32_16x16x32_bf16(
                        af[i], bfr[j], acc[i][j], 0, 0, 0);
        }
    }

#pragma unroll
    for (int i = 0; i < MI; ++i) {
#pragma unroll
        for (int j = 0; j < 2; ++j) {
            int lc = wn + j * 16 + fr;   // local col
#pragma unroll
            for (int q = 0; q < 4; ++q) {
                int lr = wm + i * 16 + fq * 4 + q;   // local row
                float v = acc[i][j][q];
                if (MODE == 0) {
                    o0[(size_t)(bm + lr) * NTOK + bn + lc] = v;
                } else if (MODE == 2) {
                    v += bias[bm + lr];
                    v = (v > 0.f) ? v + log1pf(__expf(-v)) : log1pf(__expf(v));
                    o0[(size_t)(bm + lr) * NTOK + bn + lc] = v;
                } else if (MODE == 1) {
                    int f = bm + lr;
                    if (f >= DTRANK && f < 80)
                        o2[(size_t)(f - DTRANK) * NTOK + bn + lc] = v;
                    if (bm == 0) Tt[lc * 64 + lr] = v;
                } else {  // MODE 3
                    size_t idx = (size_t)(bm + lr) * DMODEL + bn + lc;
                    float nv = o0[idx] + v;
                    o0[idx] = nv;
                    o1[idx] = f2b(nv);
                }
            }
        }
    }
    if (MODE == 1) {
        __syncthreads();
        if (bm == 0) {
            int tok = tid >> 2;
            int fb = (tid & 3) * 16;
#pragma unroll
            for (int vv = 0; vv < 4; ++vv) {
                ushort4 o;
                int f0 = fb + vv * 4;
                o.x = (f0 + 0 < DTRANK) ? f2b(Tt[tok * 64 + f0 + 0]) : 0;
                o.y = (f0 + 1 < DTRANK) ? f2b(Tt[tok * 64 + f0 + 1]) : 0;
                o.z = (f0 + 2 < DTRANK) ? f2b(Tt[tok * 64 + f0 + 2]) : 0;
                o.w = (f0 + 3 < DTRANK) ? f2b(Tt[tok * 64 + f0 + 3]) : 0;
                *(ushort4*)(o1 + (size_t)(bn + tok) * 64 + f0) = o;
            }
        }
    }
}

// ---------------- causal dwconv(K=4) + bias + SiLU ----------------
__global__ __launch_bounds__(256) void conv_k(const float* __restrict__ xzT,
                                              const float* __restrict__ cw,
                                              const float* __restrict__ cb,
                                              float* __restrict__ xiT,
                                              unsigned short* __restrict__ xib) {
    __shared__ unsigned short tile[4][256];
    int tid = threadIdx.x;
    int ch = tid >> 6;
    int d = blockIdx.x * 4 + ch;
    int b = blockIdx.y;
    int t0 = (tid & 63) * 4;
    const float* src = xzT + (size_t)d * NTOK + b * TLEN + t0;
    float4 cur = *(const float4*)src;
    float4 prev = {0.f, 0.f, 0.f, 0.f};
    if (t0 > 0) prev = *(const float4*)(src - 4);
    float w0 = cw[d * 4 + 0], w1 = cw[d * 4 + 1], w2 = cw[d * 4 + 2], w3 = cw[d * 4 + 3];
    float bb = cb[d];
    float xw[8] = {prev.x, prev.y, prev.z, prev.w, cur.x, cur.y, cur.z, cur.w};
    float4 r;
#pragma unroll
    for (int u = 0; u < 4; ++u) {
        float s = bb + w0 * xw[u + 1] + w1 * xw[u + 2] + w2 * xw[u + 3] + w3 * xw[u + 4];
        float v = s / (1.f + __expf(-s));
        ((float*)&r)[u] = v;
        tile[ch][t0 + u] = f2b(v);
    }
    *(float4*)(xiT + (size_t)d * NTOK + b * TLEN + t0) = r;
    __syncthreads();
    int t = tid;
    ushort4 o;
    o.x = tile[0][t]; o.y = tile[1][t]; o.z = tile[2][t]; o.w = tile[3][t];
    *(ushort4*)(xib + (size_t)(b * TLEN + t) * DINNER + blockIdx.x * 4) = o;
}

// ---------------- time-chunked lane-parallel selective scan ----------------
__global__ __launch_bounds__(256) void scan_k(const float* __restrict__ dtT,
                                              const float* __restrict__ xiT,
                                              const float* __restrict__ xzT,
                                              const float* __restrict__ BCt,
                                              const float* __restrict__ Alog,
                                              const float* __restrict__ Dsk,
                                              unsigned short* __restrict__ ybb) {
    __shared__ float yl[4][260];
    __shared__ float cum[4][260];
    __shared__ float hL[4][4][16];
    __shared__ float Pb[4][4][16];
    __shared__ float Hin[4][4][16];

    int tid = threadIdx.x;
    int c = tid >> 6;
    int lane = tid & 63;
    int ch = lane >> 4;
    int n = lane & 15;
    int d = blockIdx.x * 4 + ch;
    int b = blockIdx.y;
    int tl0 = c * 64;

    float a = -__expf(Alog[d * NSTATE + n]);
    const float* dtp = dtT + (size_t)d * NTOK + b * TLEN + tl0;
    const float* xip = xiT + (size_t)d * NTOK + b * TLEN + tl0;
    const float* Bp = BCt + (size_t)n * NTOK + b * TLEN + tl0;
    const float* Cp = BCt + (size_t)(NSTATE + n) * NTOK + b * TLEN + tl0;

    float h = 0.f, cd = 0.f;
    for (int t8 = 0; t8 < 64; t8 += 8) {
        float4 d0 = *(const float4*)(dtp + t8), d1 = *(const float4*)(dtp + t8 + 4);
        float4 x0 = *(const float4*)(xip + t8), x1 = *(const float4*)(xip + t8 + 4);
        float4 B0 = *(const float4*)(Bp + t8), B1 = *(const float4*)(Bp + t8 + 4);
        float4 C0 = *(const float4*)(Cp + t8), C1 = *(const float4*)(Cp + t8 + 4);
        float dts[8] = {d0.x, d0.y, d0.z, d0.w, d1.x, d1.y, d1.z, d1.w};
        float xis[8] = {x0.x, x0.y, x0.z, x0.w, x1.x, x1.y, x1.z, x1.w};
        float Bs[8] = {B0.x, B0.y, B0.z, B0.w, B1.x, B1.y, B1.z, B1.w};
        float Cs[8] = {C0.x, C0.y, C0.z, C0.w, C1.x, C1.y, C1.z, C1.w};
#pragma unroll
        for (int u = 0; u < 8; ++u) {
            cd += dts[u];
            float dA = __expf(dts[u] * a);
            h = dA * h + (dts[u] * xis[u]) * Bs[u];
            float p = h * Cs[u];
            p += __shfl_xor(p, 1);
            p += __shfl_xor(p, 2);
            p += __shfl_xor(p, 4);
            p += __shfl_xor(p, 8);
            if (n == 0) {
                yl[ch][tl0 + t8 + u] = p;
                cum[ch][tl0 + t8 + u] = cd;
            }
        }
    }
    hL[c][ch][n] = h;
    Pb[c][ch][n] = __expf(a * cd);
    __syncthreads();
    if (c == 0) {
        float H = 0.f;
        Hin[0][ch][n] = 0.f;
#pragma unroll
        for (int cc = 1; cc < 4; ++cc) {
            H = Pb[cc - 1][ch][n] * H + hL[cc - 1][ch][n];
            Hin[cc][ch][n] = H;
        }
    }
    __syncthreads();
    float Hv = Hin[c][ch][n];
    float Dv = Dsk[d];
    const float* zp = xzT + (size_t)(DINNER + d) * NTOK + b * TLEN + tl0;
    for (int t8 = 0; t8 < 64; t8 += 8) {
        float4 C0 = *(const float4*)(Cp + t8), C1 = *(const float4*)(Cp + t8 + 4);
        float4 x0 = *(const float4*)(xip + t8), x1 = *(const float4*)(xip + t8 + 4);
        float4 z0 = *(const float4*)(zp + t8), z1 = *(const float4*)(zp + t8 + 4);
        float Cs[8] = {C0.x, C0.y, C0.z, C0.w, C1.x, C1.y, C1.z, C1.w};
        float xis[8] = {x0.x, x0.y, x0.z, x0.w, x1.x, x1.y, x1.z, x1.w};
        float zs[8] = {z0.x, z0.y, z0.z, z0.w, z1.x, z1.y, z1.z, z1.w};
#pragma unroll
        for (int u = 0; u < 8; ++u) {
            float cdt = cum[ch][tl0 + t8 + u];
            float corr = Cs[u] * __expf(a * cdt) * Hv;
            corr += __shfl_xor(corr, 1);
            corr += __shfl_xor(corr, 2);
            corr += __shfl_xor(corr, 4);
            corr += __shfl_xor(corr, 8);
            if (n == 0) {
                float y = yl[ch][tl0 + t8 + u] + corr + Dv * xis[u];
                float zz = zs[u];
                y *= zz / (1.f + __expf(-zz));
                yl[ch][tl0 + t8 + u] = y;
            }
        }
    }
    __syncthreads();
    {
        int t = tid;
        ushort4 o;
        o.x = f2b(yl[0][t]);
        o.y = f2b(yl[1][t]);
        o.z = f2b(yl[2][t]);
        o.w = f2b(yl[3][t]);
        *(ushort4*)(ybb + (size_t)(b * TLEN + t) * DINNER + blockIdx.x * 4) = o;
    }
}

// ---------------- RMSNorm ----------------
__global__ __launch_bounds__(256) void rmsnorm_k(const float* __restrict__ x,
                                                 const float* __restrict__ nw,
                                                 float* __restrict__ out) {
    int row = blockIdx.x;
    const float* xr = x + (size_t)row * DMODEL;
    int tid = threadIdx.x;
    float s = 0.f;
    for (int d = tid; d < DMODEL; d += 256) {
        float v = xr[d];
        s += v * v;
    }
#pragma unroll
    for (int off = 32; off >= 1; off >>= 1) s += __shfl_down(s, off);
    __shared__ float red[4];
    __shared__ float scale;
    int wid = tid >> 6, lane = tid & 63;
    if (lane == 0) red[wid] = s;
    __syncthreads();
    if (tid == 0) {
        float tot = red[0] + red[1] + red[2] + red[3];
        scale = rsqrtf(tot / (float)DMODEL + 1e-5f);
    }
    __syncthreads();
    float sc = scale;
    for (int d = tid; d < DMODEL; d += 256)
        out[(size_t)row * DMODEL + d] = xr[d] * sc * nw[d];
}

extern "C" void kernel_launch(void* const* d_in, const int* in_sizes, int n_in,
                              void* d_out, int out_size, void* d_ws, size_t ws_size,
                              hipStream_t stream) {
    const int* ids = (const int*)d_in[0];
    const float* emb = (const float*)d_in[1];
    const float* pos = (const float*)d_in[2];
    const float* ipw = (const float*)d_in[3];
    const float* cw = (const float*)d_in[4];
    const float* cb = (const float*)d_in[5];
    const float* xpw = (const float*)d_in[6];
    const float* dpw = (const float*)d_in[7];
    const float* dpb = (const float*)d_in[8];
    const float* Alog = (const float*)d_in[9];
    const float* Dsk = (const float*)d_in[10];
    const float* opw = (const float*)d_in[11];
    const float* nw = (const float*)d_in[12];

    float* x = (float*)d_ws;                   // 786432
    float* xzT = x + 786432;                   // 3145728
    float* xiT = xzT + 3145728;                // 1572864
    float* dtT = xiT + 1572864;                // 1572864
    float* BCt = dtT + 1572864;                // 32768
    unsigned short* xb = (unsigned short*)(BCt + 32768);  // 786432
    unsigned short* xib = xb + 786432;         // 1572864
    unsigned short* ybb = xib + 1572864;       // 1572864
    unsigned short* xdblb = ybb + 1572864;     // 65536
    unsigned short* w_ip = xdblb + 65536;      // S_IP
    unsigned short* w_op = w_ip + S_IP;        // S_OP
    unsigned short* w_xp = w_op + S_OP;        // S_XP2
    unsigned short* w_dt = w_xp + S_XP2;       // S_DT

    embed_k<<<NTOK * DMODEL / 256, 256, 0, stream>>>(ids, emb, pos, x, xb);

    for (int l = 0; l < NLAYER; ++l) {
        const float* ipw_l = ipw + (size_t)l * S_IP;
        const float* cw_l = cw + (size_t)l * DINNER * 4;
        const float* cb_l = cb + (size_t)l * DINNER;
        const float* xpw_l = xpw + (size_t)l * 80 * 1536;
        const float* dpw_l = dpw + (size_t)l * DINNER * DTRANK;
        const float* dpb_l = dpb + (size_t)l * DINNER;
        const float* Alog_l = Alog + (size_t)l * DINNER * NSTATE;
        const float* Dsk_l = Dsk + (size_t)l * DINNER;
        const float* opw_l = opw + (size_t)l * S_OP;

        wconv_k<<<(S_IP + S_OP + S_XP2 + S_DT) / 1024, 256, 0, stream>>>(
            ipw_l, opw_l, xpw_l, dpw_l, w_ip, w_op, w_xp, w_dt);

        // xzT[e][tok] : A=w_ip rows=e, B=xb rows=tok
        mgemm_k<128, 0><<<dim3(3072 / 128, NTOK / 64), 256, 0, stream>>>(
            w_ip, DMODEL, xb, DMODEL, DMODEL, nullptr, xzT, nullptr, nullptr);
        // conv + silu -> xiT f32, xib bf16
        conv_k<<<dim3(DINNER / 4, BATCH), 256, 0, stream>>>(xzT, cw_l, cb_l, xiT, xib);
        // x_proj: A=w_xp(pad128) rows=feat, B=xib rows=tok -> BCt + xdblb
        mgemm_k<64, 1><<<dim3(2, NTOK / 64), 256, 0, stream>>>(
            w_xp, DINNER, xib, DINNER, DINNER, nullptr, nullptr, xdblb, BCt);
        // dtT[d][tok] = softplus(...): A=w_dt rows=d, B=xdblb rows=tok, K=64
        mgemm_k<128, 2><<<dim3(DINNER / 128, NTOK / 64), 256, 0, stream>>>(
            w_dt, 64, xdblb, 64, 64, dpb_l, dtT, nullptr, nullptr);
        // scan
        scan_k<<<dim3(DINNER / 4, BATCH), 256, 0, stream>>>(
            dtT, xiT, xzT, BCt, Alog_l, Dsk_l, ybb);
        // out_proj: A=ybb rows=tok, B=w_op rows=d; x += , xb = bf16(x)
        mgemm_k<128, 3><<<dim3(NTOK / 128, DMODEL / 64), 256, 0, stream>>>(
            ybb, DINNER, w_op, DINNER, DINNER, nullptr, x, xb, nullptr);
    }

    rmsnorm_k<<<NTOK, 256, 0, stream>>>(x, nw, (float*)d_out);
}